// Round 14
// baseline (375.996 us; speedup 1.0000x reference)
//
#include <hip/hip_runtime.h>

// Problem constants (from reference): B=128, N=512, H=256, F_JET=8, gin=776.
#define B_   128
#define N_   512
#define H_   256
#define FJ   8
#define ROWS (B_ * N_)          // 65536 flattened vertex rows
#define NEGV (-1e9f)

typedef _Float16 f16;
typedef __attribute__((ext_vector_type(8)))  f16   f16x8;    // MFMA A/B fragment (4 VGPRs)
typedef __attribute__((ext_vector_type(4)))  float f32x4;    // 16x16 C/D fragment
typedef __attribute__((ext_vector_type(16))) float f32x16;   // 32x32 C/D fragment

static __device__ inline f32x4 MFMA16(f16x8 a, f16x8 b, f32x4 c) {
  return __builtin_amdgcn_mfma_f32_16x16x32_f16(a, b, c, 0, 0, 0);
}
static __device__ inline f32x16 MFMA32(f16x8 a, f16x8 b, f32x16 c) {
  return __builtin_amdgcn_mfma_f32_32x32x16_f16(a, b, c, 0, 0, 0);
}

// global -> LDS direct copy, 16B per lane. LDS ptr must be wave-uniform; HW adds lane*16.
static __device__ inline void gld16(const void* g, void* l) {
  __builtin_amdgcn_global_load_lds(
      (const __attribute__((address_space(1))) void*)g,
      (__attribute__((address_space(3))) void*)(uintptr_t)l,
      16, 0, 0);
}

// pack two f32 -> 2 f16 in one u32 (v_cvt_pkrtz_f16_f32)
static __device__ inline uint32_t pkrtz(float a, float b) {
  auto v = __builtin_amdgcn_cvt_pkrtz(a, b);
  return __builtin_bit_cast(uint32_t, v);
}
static __device__ inline float tanhfast(float x) {
  float e = __expf(2.f * x);
  return 1.f - 2.f / (e + 1.f);
}

// XCD-aware bijective block remap (T1): launch slot s -> original block o.
// Forward map (o -> slot) is s = (o&7)*C + (o>>3), C = nwg/8 (power of 2).
// 8 consecutive original blocks (sharing operand panels) land on ONE XCD.
#define XCD_O(LG_C) ((int)(((blockIdx.x & ((1u << (LG_C)) - 1)) << 3) | (blockIdx.x >> (LG_C))))

// ---------------------------------------------------------------------------
// Prep: transpose/convert weights to fp16 with the BK=32 LDS bank-swizzle
// BAKED IN: within each 32k window (4 chunks of 16B), chunk c2=(k>>3)&3 is
// stored at slot c2 ^ ((n>>1)&3)  (n = image row).  Read side XORs the same.
// ---------------------------------------------------------------------------
__global__ void k_prep(const float* __restrict__ Wa, const float* __restrict__ Wm,
                       const float* __restrict__ Wz, const float* __restrict__ Wr,
                       const float* __restrict__ Wh,
                       f16* __restrict__ WaT, f16* __restrict__ WmT,
                       f16* __restrict__ WzrT, f16* __restrict__ WhcT) {
  int idx = blockIdx.x * 256 + threadIdx.x;
  if (idx < 65536) {
    int d = idx >> 8, k = idx & 255;
    int kk = (k & ~31) | (((((k >> 3) & 3) ^ ((d >> 1) & 3)) << 3) | (k & 7));
    WaT[d * 256 + kk] = (f16)Wa[k * 256 + d];
  } else if (idx < 131072) {
    int t = idx - 65536;
    int d = t >> 8, k = t & 255;
    int kk = (k & ~31) | (((((k >> 3) & 3) ^ ((d >> 1) & 3)) << 3) | (k & 7));
    WmT[d * 256 + kk] = (f16)Wm[k * 256 + d];
  } else if (idx < 131072 + 262144) {
    int t = idx - 131072;
    int n = t >> 9, k = t & 511;
    const float* src = (n < 256) ? Wz : Wr;
    int np  = n & 255;
    int row = (k < 256) ? k : (264 + k);   // 520 + (k - 256)
    int kk = (k & ~31) | (((((k >> 3) & 3) ^ ((n >> 1) & 3)) << 3) | (k & 7));
    WzrT[n * 512 + kk] = (f16)src[row * 256 + np];
  } else {
    int t = idx - (131072 + 262144);       // < 131072
    int n = t >> 9, k = t & 511;
    int row = (k < 256) ? k : (264 + k);
    int kk = (k & ~31) | (((((k >> 3) & 3) ^ ((n >> 1) & 3)) << 3) | (k & 7));
    WhcT[n * 512 + kk] = (f16)Wh[row * 256 + n];
  }
}

// FUSED: partial column sums AND f16 image of h in one pass over h.
__global__ void k_hmean(const float* __restrict__ h, float* __restrict__ hmean4,
                        f16* __restrict__ h16) {
  int b = blockIdx.x, part = blockIdx.y, d = threadIdx.x;
  size_t base = ((size_t)b * N_ + part * 128) * H_ + d;
  const float* p = h + base;
  f16* p16 = h16 + base;
  float s = 0.f;
  #pragma unroll 8
  for (int n = 0; n < 128; ++n) {
    float v = p[n * H_];
    s += v;
    p16[n * H_] = (f16)v;
  }
  hmean4[(b * 4 + part) * H_ + d] = s;
}

// Per-batch GRU constants: c_*[b][d] = bias[d] + h_mean[b]·W*[256:512,d] + jets[b]·W*[512:520,d]
__global__ void k_cvec(const float* __restrict__ hmean4, const float* __restrict__ jets,
                       const float* __restrict__ Wz, const float* __restrict__ Wr,
                       const float* __restrict__ Wh,
                       const float* __restrict__ bz, const float* __restrict__ br,
                       const float* __restrict__ bh,
                       float* __restrict__ cz, float* __restrict__ cr, float* __restrict__ ch) {
  __shared__ float hm[H_];
  __shared__ float jt[FJ];
  int b = blockIdx.x, d = threadIdx.x;
  hm[d] = (hmean4[(b * 4 + 0) * H_ + d] + hmean4[(b * 4 + 1) * H_ + d] +
           hmean4[(b * 4 + 2) * H_ + d] + hmean4[(b * 4 + 3) * H_ + d]) * (1.f / N_);
  if (d < FJ) jt[d] = jets[b * FJ + d];
  __syncthreads();
  float az = bz[d], ar = br[d], ah = bh[d];
  #pragma unroll 4
  for (int k = 0; k < H_; ++k) {
    float m = hm[k];
    az += m * Wz[(256 + k) * 256 + d];
    ar += m * Wr[(256 + k) * 256 + d];
    ah += m * Wh[(256 + k) * 256 + d];
  }
  #pragma unroll
  for (int f = 0; f < FJ; ++f) {
    float j = jt[f];
    az += j * Wz[(512 + f) * 256 + d];
    ar += j * Wr[(512 + f) * 256 + d];
    ah += j * Wh[(512 + f) * 256 + d];
  }
  cz[b * H_ + d] = az;
  cr[b * H_ + d] = ar;
  ch[b * H_ + d] = ah;
}

// ===========================================================================
// Shared GEMM geometry (R14): 128x128 tile, 4 waves 2x2 (wave 64x64,
// acc[4][4]), BK=32, SINGLE-buffered LDS (A 8KB + B 8KB = 16KB ->
// min(10 LDS-blocks, 6 VGPR-waves/SIMD) = 24 waves/CU, 75% theoretical).
// Per-iteration ledger: stage(kt) [4 gld16] -> vmcnt(0) -> barrier ->
// compute -> barrier.  Race-free (single buffer, full drain).
//
// LDS tile layout: [128 rows][32 k] f16, row = 64B = 4 chunks of 16B.
// Chunk slot s of row r holds source chunk s ^ ((r>>1)&3).  All row bases
// (m0, wave*32, i*16, wr, mi*16) are ≡0 mod 8, so the key reduces to
// (l>>3)&3 on the stage side and (m16>>1)&3 on the read side.
// Bank check (per quarter-wave, 16 lanes): window = 4(row&1) + slot spans
// 8 values x2 lanes -> 2-way -> free (m136).
// ===========================================================================
#define GEMM_PRE()                                                      \
  const int tid = threadIdx.x, lane = tid & 63, wave = tid >> 6;        \
  const int g = lane >> 4, m16 = lane & 15;                             \
  const int wr = (wave >> 1) * 64, wc = (wave & 1) * 64;                \
  f32x4 acc[4][4] = {};

#define GEMM_COMPUTE32(Ab, Bb)                                          \
  {                                                                     \
    f16x8 af[4], bf[4];                                                 \
    _Pragma("unroll")                                                   \
    for (int mi = 0; mi < 4; ++mi)                                      \
      af[mi] = *(const f16x8*)((const char*)(Ab) + (wr + mi * 16 + m16) * 64 \
                               + ((g ^ ((m16 >> 1) & 3)) << 4));        \
    _Pragma("unroll")                                                   \
    for (int ni = 0; ni < 4; ++ni)                                      \
      bf[ni] = *(const f16x8*)((const char*)(Bb) + (wc + ni * 16 + m16) * 64 \
                               + ((g ^ ((m16 >> 1) & 3)) << 4));        \
    _Pragma("unroll")                                                   \
    for (int mi = 0; mi < 4; ++mi)                                      \
      _Pragma("unroll")                                                 \
      for (int ni = 0; ni < 4; ++ni)                                    \
        acc[mi][ni] = MFMA16(af[mi], bf[ni], acc[mi][ni]);              \
  }

// STGX/STGY each issue exactly 2 gld16 for K-cols k0..k0+31.
#define GEMM_LOOP32(KMAX, STGX, STGY)                                   \
  for (int kt = 0; kt < (KMAX) / 32; ++kt) {                            \
    STGX(kt * 32);                                                      \
    STGY(kt * 32);                                                      \
    asm volatile("s_waitcnt vmcnt(0)" ::: "memory");                    \
    __builtin_amdgcn_sched_barrier(0);                                  \
    __builtin_amdgcn_s_barrier();                                       \
    __builtin_amdgcn_sched_barrier(0);                                  \
    GEMM_COMPUTE32(&AL[0], &BL[0]);                                     \
    __builtin_amdgcn_s_barrier();                                       \
    __builtin_amdgcn_sched_barrier(0);                                  \
  }

// per-lane source offsets (BK=32; 16 rows per gld16, lane l -> row l>>2,
// chunk l&3; linear sources get the XOR on the source chunk).
#define SRC_SWZ32(row0, RS) ((size_t)(row0 + wave * 32 + (lane >> 2)) * (RS) \
                             + (size_t)(((lane & 3) ^ ((lane >> 3) & 3)) << 4))
#define SRC_IMG32(row0, RS) ((size_t)(row0 + wave * 32 + (lane >> 2)) * (RS) \
                             + (size_t)((lane & 3) << 4))

// ---------------------------------------------------------------------------
// q = f16(h @ Wa + ba). 1024 blocks XCD-swizzled; o: n = o&1, m = o>>1.
// ---------------------------------------------------------------------------
__global__ __launch_bounds__(256) void k_gemm_q(
    const f16* __restrict__ h16, const f16* __restrict__ WaT,
    const float* __restrict__ ba, f16* __restrict__ q) {
  __shared__ __align__(16) f16 AL[128 * 32], BL[128 * 32];
  GEMM_PRE();
  const int o = XCD_O(7);                       // C = 128
  const int m0 = (o >> 1) * 128, n0 = (o & 1) * 128;
  const size_t a_off = SRC_SWZ32(m0, 512);
  const size_t b_off = SRC_IMG32(n0, 512);
  #define STGX_Q(k0)                                                    \
    {                                                                   \
      const char* sa = (const char*)h16 + a_off + (size_t)(k0) * 2;     \
      char* da = (char*)&AL[0] + wave * 2048;                           \
      gld16(sa, da);                                                    \
      gld16(sa + 16 * 512, da + 1024);                                  \
    }
  #define STGY_Q(k0)                                                    \
    {                                                                   \
      const char* sb = (const char*)WaT + b_off + (size_t)(k0) * 2;     \
      char* db = (char*)&BL[0] + wave * 2048;                           \
      gld16(sb, db);                                                    \
      gld16(sb + 16 * 512, db + 1024);                                  \
    }
  GEMM_LOOP32(256, STGX_Q, STGY_Q);
  #pragma unroll
  for (int mi = 0; mi < 4; ++mi)
    #pragma unroll
    for (int ni = 0; ni < 4; ++ni) {
      int gcol = n0 + wc + ni * 16 + m16;
      float bias = ba[gcol];
      #pragma unroll
      for (int r = 0; r < 4; ++r) {
        int grow = m0 + wr + mi * 16 + 4 * g + r;
        q[(size_t)grow * 256 + gcol] = (f16)(acc[mi][ni][r] + bias);
      }
    }
}

// ---------------------------------------------------------------------------
// hmT[b][d][n] = f16( (h[b] @ Wm + bm)^T ). 1024 blocks; o: tile = o&7, b = o>>3.
// A = WmT image (baked BK32 swizzle), B = h16 (linear, source swizzle).
// ---------------------------------------------------------------------------
__global__ __launch_bounds__(256) void k_gemm_hmT(
    const f16* __restrict__ h16, const f16* __restrict__ WmT,
    const float* __restrict__ bm, f16* __restrict__ hmT) {
  __shared__ __align__(16) f16 AL[128 * 32], BL[128 * 32];
  GEMM_PRE();
  const int o = XCD_O(7);                       // C = 128
  const int b = o >> 3;
  const int m0 = ((o & 7) >> 2) * 128, n0 = (o & 3) * 128;
  const size_t a_off = SRC_IMG32(m0, 512);
  const size_t b_off = SRC_SWZ32(b * 512 + n0, 512);
  #define STGX_HM(k0)                                                   \
    {                                                                   \
      const char* sb = (const char*)h16 + b_off + (size_t)(k0) * 2;     \
      char* db = (char*)&BL[0] + wave * 2048;                           \
      gld16(sb, db);                                                    \
      gld16(sb + 16 * 512, db + 1024);                                  \
    }
  #define STGY_HM(k0)                                                   \
    {                                                                   \
      const char* sa = (const char*)WmT + a_off + (size_t)(k0) * 2;     \
      char* da = (char*)&AL[0] + wave * 2048;                           \
      gld16(sa, da);                                                    \
      gld16(sa + 16 * 512, da + 1024);                                  \
    }
  GEMM_LOOP32(256, STGX_HM, STGY_HM);
  #pragma unroll
  for (int mi = 0; mi < 4; ++mi)
    #pragma unroll
    for (int r = 0; r < 4; ++r) {
      int d = m0 + wr + mi * 16 + 4 * g + r;
      float bias = bm[d];
      #pragma unroll
      for (int ni = 0; ni < 4; ++ni) {
        int n = n0 + wc + ni * 16 + m16;
        hmT[(size_t)b * H_ * N_ + (size_t)d * N_ + n] = (f16)(acc[mi][ni][r] + bias);
      }
    }
}

// ---------------------------------------------------------------------------
// Flash attention + DTNN message, v7 (UNCHANGED from R13 — passing).
// ---------------------------------------------------------------------------
__global__ __launch_bounds__(256, 2) void k_attn7(
    const f16* __restrict__ q, const float* __restrict__ mask,
    const f16* __restrict__ hmT, const f16* __restrict__ h16,
    f16* __restrict__ msg) {
  __shared__ __align__(16) f16 Kt[2][32 * 256];   // 2 x 16KB
  __shared__ __align__(16) f16 Vt[2][256 * 32];   // 2 x 16KB
  __shared__ float mask_lds[N_];
  const int tid = threadIdx.x, lane = tid & 63, wave = tid >> 6;
  const int l31 = lane & 31, hi = lane >> 5;
  const int o = XCD_O(6);                        // C = 64
  const int b = o & 127, i0 = (o >> 7) * 128 + wave * 32;

  mask_lds[tid]       = mask[b * N_ + tid];
  mask_lds[tid + 256] = mask[b * N_ + tid + 256];

  const f16* qrow = q + (size_t)(b * N_ + i0 + l31) * H_ + hi * 8;
  f16x8 qb[16];
  #pragma unroll
  for (int s5 = 0; s5 < 16; ++s5) qb[s5] = *(const f16x8*)(qrow + s5 * 16);

  f32x16 ot[8] = {};          // O^T: 8 d-tiles x 16 f32
  float mrun = -3.0e38f, lrun = 0.f;

  const char* hvbs = (const char*)(hmT + (size_t)b * H_ * N_);
  const char* h16b = (const char*)(h16 + (size_t)b * N_ * H_);

  auto stageK = [&](int buf, int jt) {
    const int rl = lane >> 5, s5 = lane & 31;
    char* dst = (char*)&Kt[buf][0] + wave * 4096;
    #pragma unroll
    for (int i = 0; i < 4; ++i) {
      int row = wave * 8 + i * 2 + rl;
      const char* src = h16b + (size_t)(jt * 32 + row) * 512
                      + (size_t)((s5 ^ (row & 7)) << 4);
      gld16(src, dst + i * 1024);
    }
  };
  auto stageV = [&](int buf, int jt) {
    const int swz = ((lane & 3) ^ ((lane >> 3) & 3)) << 4;
    char* dst = (char*)&Vt[buf][0] + wave * 4096;
    #pragma unroll
    for (int i = 0; i < 4; ++i) {
      int d = wave * 64 + i * 16 + (lane >> 2);
      gld16(hvbs + (size_t)d * 1024 + jt * 64 + swz, dst + i * 1024);
    }
  };

  __syncthreads();            // mask_lds visible before first use
  stageK(0, 0); stageV(0, 0); // 8 gld16
  __builtin_amdgcn_sched_barrier(0);

  const int x7 = lane & 7, x3 = (l31 >> 1) & 3;

  for (int jt = 0; jt < 16; ++jt) {
    const int cur = jt & 1, j0 = jt * 32;
    if (jt < 15) {
      stageK(cur ^ 1, jt + 1); stageV(cur ^ 1, jt + 1);
      asm volatile("s_waitcnt vmcnt(8)" ::: "memory");
    } else {
      asm volatile("s_waitcnt vmcnt(0)" ::: "memory");
    }
    __builtin_amdgcn_sched_barrier(0);
    __builtin_amdgcn_s_barrier();      // cur K/V visible; prev-buf reads done
    __builtin_amdgcn_sched_barrier(0);

    // ---- S^T = K · Q^T  (16 slabs of K=16)
    const char* kb = (const char*)&Kt[cur][0] + l31 * 512;
    f32x16 st = {};
    __builtin_amdgcn_s_setprio(1);
    #pragma unroll
    for (int s5 = 0; s5 < 16; ++s5) {
      f16x8 kf = *(const f16x8*)(kb + (((s5 * 2 + hi) ^ x7) << 4));
      st = MFMA32(kf, qb[s5], st);
    }
    __builtin_amdgcn_s_setprio(0);

    // ---- in-register online softmax
    float pm = st[0];
    #pragma unroll
    for (int r = 1; r < 16; ++r) pm = fmaxf(pm, st[r]);
    pm = fmaxf(pm, __shfl_xor(pm, 32, 64));
    if (!__all(pm <= mrun + 8.f)) {      // defer-max (T13)
      float mn = fmaxf(mrun, pm);
      float al = __expf(mrun - mn);
      lrun *= al;
      #pragma unroll
      for (int dt = 0; dt < 8; ++dt)
        #pragma unroll
        for (int e = 0; e < 16; ++e) ot[dt][e] *= al;
      mrun = mn;
    }
    float p[16], ts = 0.f;
    #pragma unroll
    for (int r = 0; r < 16; ++r) {
      float mk = mask_lds[j0 + (r & 3) + 8 * (r >> 2) + 4 * hi];
      p[r] = __expf(st[r] - mrun) * mk;
      ts += p[r];
    }
    ts += __shfl_xor(ts, 32, 64);
    lrun += ts;

    // ---- pack P -> f16 B-frags via shfl_xor(32) redistribution
    f16x8 pf[2];
    #pragma unroll
    for (int kk = 0; kk < 2; ++kk) {
      uint32_t pk01 = pkrtz(p[kk * 8 + 0], p[kk * 8 + 1]);
      uint32_t pk23 = pkrtz(p[kk * 8 + 2], p[kk * 8 + 3]);
      uint32_t pk45 = pkrtz(p[kk * 8 + 4], p[kk * 8 + 5]);
      uint32_t pk67 = pkrtz(p[kk * 8 + 6], p[kk * 8 + 7]);
      uint32_t s01 = __shfl_xor(pk01, 32, 64);
      uint32_t s23 = __shfl_xor(pk23, 32, 64);
      uint32_t s45 = __shfl_xor(pk45, 32, 64);
      uint32_t s67 = __shfl_xor(pk67, 32, 64);
      union { uint32_t u[4]; f16x8 v; } w;
      w.u[0] = hi ? s45 : pk01;
      w.u[1] = hi ? s67 : pk23;
      w.u[2] = hi ? pk45 : s01;
      w.u[3] = hi ? pk67 : s23;
      pf[kk] = w.v;
    }

    // ---- O^T += V^T · P^T
    const char* vb = (const char*)&Vt[cur][0] + l31 * 64;
    __builtin_amdgcn_s_setprio(1);
    #pragma unroll
    for (int kk = 0; kk < 2; ++kk)
      #pragma unroll
      for (int dt = 0; dt < 8; ++dt) {
        f16x8 vf = *(const f16x8*)(vb + dt * 2048 + (((kk * 2 + hi) ^ x3) << 4));
        ot[dt] = MFMA32(vf, pf[kk], ot[dt]);
      }
    __builtin_amdgcn_s_setprio(0);

    __builtin_amdgcn_s_barrier();      // all reads of cur done before overwrite
    __builtin_amdgcn_sched_barrier(0);
  }

  // ---- epilogue: msg[i][d] = tanh(rm * O^T[d][i] / l), packed 8B stores
  float rm  = mask_lds[i0 + l31];
  float inv = rm / lrun;
  f16* msgp = msg + (size_t)(b * N_ + i0 + l31) * H_;
  #pragma unroll
  for (int dt = 0; dt < 8; ++dt)
    #pragma unroll
    for (int rg = 0; rg < 4; ++rg) {
      float t0 = tanhfast(ot[dt][rg * 4 + 0] * inv);
      float t1 = tanhfast(ot[dt][rg * 4 + 1] * inv);
      float t2 = tanhfast(ot[dt][rg * 4 + 2] * inv);
      float t3 = tanhfast(ot[dt][rg * 4 + 3] * inv);
      union { uint32_t u[2]; uint64_t q; } w;
      w.u[0] = pkrtz(t0, t1); w.u[1] = pkrtz(t2, t3);
      *(uint64_t*)(msgp + dt * 32 + rg * 8 + 4 * hi) = w.q;
    }
}

// ---------------------------------------------------------------------------
// Gate GEMM 1: pre = [msg|h] @ Wzr + c. 2048 blocks; o: n = o&3, m = o>>2.
// ---------------------------------------------------------------------------
__global__ __launch_bounds__(256) void k_gemm_zr(
    const f16* __restrict__ msg, const f16* __restrict__ h16,
    const f16* __restrict__ WzrT, const float* __restrict__ cz,
    const float* __restrict__ cr, f16* __restrict__ z, f16* __restrict__ rh) {
  __shared__ __align__(16) f16 AL[128 * 32], BL[128 * 32];
  GEMM_PRE();
  const int o = XCD_O(8);                       // C = 256
  const int m0 = (o >> 2) * 128;
  const int nx = o & 3;
  const int n0 = nx * 128;
  const size_t a_off = SRC_SWZ32(m0, 512);
  const size_t b_off = SRC_IMG32(n0, 1024);
  #define STGX_ZR(k0)                                                   \
    {                                                                   \
      const char* ab = (const char*)((k0) < 256 ? msg : h16);           \
      const char* sa = ab + a_off + (size_t)(((k0) & 255)) * 2;         \
      char* da = (char*)&AL[0] + wave * 2048;                           \
      gld16(sa, da);                                                    \
      gld16(sa + 16 * 512, da + 1024);                                  \
    }
  #define STGY_ZR(k0)                                                   \
    {                                                                   \
      const char* sb = (const char*)WzrT + b_off + (size_t)(k0) * 2;    \
      char* db = (char*)&BL[0] + wave * 2048;                           \
      gld16(sb, db);                                                    \
      gld16(sb + 16 * 1024, db + 1024);                                 \
    }
  GEMM_LOOP32(512, STGX_ZR, STGY_ZR);
  const int is_r = nx >> 1;
  #pragma unroll
  for (int mi = 0; mi < 4; ++mi)
    #pragma unroll
    for (int ni = 0; ni < 4; ++ni) {
      int ncol = (nx & 1) * 128 + wc + ni * 16 + m16;
      #pragma unroll
      for (int r = 0; r < 4; ++r) {
        int grow = m0 + wr + mi * 16 + 4 * g + r;
        int bb = grow >> 9;
        float a = acc[mi][ni][r];
        size_t oidx = (size_t)grow * 256 + ncol;
        if (!is_r) {
          float v = a + cz[bb * 256 + ncol];
          z[oidx] = (f16)(1.f / (1.f + __expf(-v)));
        } else {
          float v  = a + cr[bb * 256 + ncol];
          float rr = 1.f / (1.f + __expf(-v));
          rh[oidx] = (f16)(rr * (float)h16[oidx]);
        }
      }
    }
}

// ---------------------------------------------------------------------------
// Gate GEMM 2: h_tilde = tanh([msg|rh] @ Whc + c_h); out = (1-z)*h + z*h_tilde
// 1024 blocks; o: n = o&1, m = o>>1.
// ---------------------------------------------------------------------------
__global__ __launch_bounds__(256) void k_gemm_ht(
    const f16* __restrict__ msg, const f16* __restrict__ rh,
    const f16* __restrict__ WhcT, const float* __restrict__ ch,
    const f16* __restrict__ z, const f16* __restrict__ h16,
    float* __restrict__ out) {
  __shared__ __align__(16) f16 AL[128 * 32], BL[128 * 32];
  GEMM_PRE();
  const int o = XCD_O(7);                       // C = 128
  const int m0 = (o >> 1) * 128;
  const int n0 = (o & 1) * 128;
  const size_t a_off = SRC_SWZ32(m0, 512);
  const size_t b_off = SRC_IMG32(n0, 1024);
  #define STGX_HT(k0)                                                   \
    {                                                                   \
      const char* ab = (const char*)((k0) < 256 ? msg : rh);            \
      const char* sa = ab + a_off + (size_t)(((k0) & 255)) * 2;         \
      char* da = (char*)&AL[0] + wave * 2048;                           \
      gld16(sa, da);                                                    \
      gld16(sa + 16 * 512, da + 1024);                                  \
    }
  #define STGY_HT(k0)                                                   \
    {                                                                   \
      const char* sb = (const char*)WhcT + b_off + (size_t)(k0) * 2;    \
      char* db = (char*)&BL[0] + wave * 2048;                           \
      gld16(sb, db);                                                    \
      gld16(sb + 16 * 1024, db + 1024);                                 \
    }
  GEMM_LOOP32(512, STGX_HT, STGY_HT);
  #pragma unroll
  for (int mi = 0; mi < 4; ++mi)
    #pragma unroll
    for (int ni = 0; ni < 4; ++ni) {
      int gcol = n0 + wc + ni * 16 + m16;
      #pragma unroll
      for (int r = 0; r < 4; ++r) {
        int grow = m0 + wr + mi * 16 + 4 * g + r;
        int bb = grow >> 9;
        size_t oidx = (size_t)grow * 256 + gcol;
        float pre = acc[mi][ni][r] + ch[bb * 256 + gcol];
        float htl = tanhf(pre);
        float zv  = (float)z[oidx];
        float hv  = (float)h16[oidx];
        out[oidx] = (1.f - zv) * hv + zv * htl;
      }
    }
}

// ---------------------------------------------------------------------------
extern "C" void kernel_launch(void* const* d_in, const int* in_sizes, int n_in,
                              void* d_out, int out_size, void* d_ws, size_t ws_size,
                              hipStream_t stream) {
  const float* h    = (const float*)d_in[0];
  const float* jets = (const float*)d_in[1];
  const float* mask = (const float*)d_in[2];
  const float* Wa   = (const float*)d_in[3];
  const float* ba   = (const float*)d_in[4];
  const float* Wm   = (const float*)d_in[5];
  const float* bm   = (const float*)d_in[6];
  const float* Wz   = (const float*)d_in[7];
  const float* bz   = (const float*)d_in[8];
  const float* Wr   = (const float*)d_in[9];
  const float* br   = (const float*)d_in[10];
  const float* Wh   = (const float*)d_in[11];
  const float* bh   = (const float*)d_in[12];
  float* out = (float*)d_out;

  char* ws = (char*)d_ws;
  size_t off = 0;
  auto alloc = [&](size_t bytes) -> void* {
    void* p = ws + off;
    off += (bytes + 255) & ~(size_t)255;
    return p;
  };
  // big: q (f16, 32MB) during attention; z (f16) + rh (f16) afterwards.
  char*   big   = (char*) alloc((size_t)ROWS * H_ * 4);
  f16*    hmT   = (f16*)  alloc((size_t)B_ * H_ * N_ * 2);
  f16*    msg   = (f16*)  alloc((size_t)ROWS * H_ * 2);
  f16*    h16   = (f16*)  alloc((size_t)ROWS * H_ * 2);
  float*  hmean4= (float*)alloc((size_t)B_ * 4 * H_ * 4);
  float*  cz    = (float*)alloc((size_t)B_ * H_ * 4);
  float*  cr    = (float*)alloc((size_t)B_ * H_ * 4);
  float*  chv   = (float*)alloc((size_t)B_ * H_ * 4);
  f16*    WaT   = (f16*)  alloc(65536 * 2);
  f16*    WmT   = (f16*)  alloc(65536 * 2);
  f16*    WzrT  = (f16*)  alloc(262144 * 2);
  f16*    WhcT  = (f16*)  alloc(131072 * 2);
  f16* q  = (f16*)big;
  f16* z  = (f16*)big;                                     // q dead after attn
  f16* rh = (f16*)(big + (size_t)ROWS * H_ * 2);
  if (off > ws_size) return;  // workspace insufficient

  k_prep    <<<2048, 256, 0, stream>>>(Wa, Wm, Wz, Wr, Wh, WaT, WmT, WzrT, WhcT);
  k_hmean   <<<dim3(B_, 4), H_, 0, stream>>>(h, hmean4, h16);
  k_cvec    <<<B_, H_, 0, stream>>>(hmean4, jets, Wz, Wr, Wh, bz, br, bh, cz, cr, chv);
  k_gemm_q  <<<1024, 256, 0, stream>>>(h16, WaT, ba, q);
  k_gemm_hmT<<<1024, 256, 0, stream>>>(h16, WmT, bm, hmT);
  k_attn7   <<<512, 256, 0, stream>>>(q, mask, hmT, h16, msg);
  k_gemm_zr <<<2048, 256, 0, stream>>>(msg, h16, WzrT, cz, cr, z, rh);
  k_gemm_ht <<<1024, 256, 0, stream>>>(msg, rh, WhcT, chv, z, h16, out);
}

// Round 15
// 345.531 us; speedup vs baseline: 1.0882x; 1.0882x over previous
//
#include <hip/hip_runtime.h>

// Problem constants (from reference): B=128, N=512, H=256, F_JET=8, gin=776.
#define B_   128
#define N_   512
#define H_   256
#define FJ   8
#define ROWS (B_ * N_)          // 65536 flattened vertex rows
#define NEGV (-1e9f)

typedef _Float16 f16;
typedef __attribute__((ext_vector_type(8)))  f16   f16x8;    // MFMA A/B fragment (4 VGPRs)
typedef __attribute__((ext_vector_type(4)))  float f32x4;    // 16x16 C/D fragment
typedef __attribute__((ext_vector_type(16))) float f32x16;   // 32x32 C/D fragment

static __device__ inline f32x4 MFMA16(f16x8 a, f16x8 b, f32x4 c) {
  return __builtin_amdgcn_mfma_f32_16x16x32_f16(a, b, c, 0, 0, 0);
}
static __device__ inline f32x16 MFMA32(f16x8 a, f16x8 b, f32x16 c) {
  return __builtin_amdgcn_mfma_f32_32x32x16_f16(a, b, c, 0, 0, 0);
}

// global -> LDS direct copy, 16B per lane. LDS ptr must be wave-uniform; HW adds lane*16.
static __device__ inline void gld16(const void* g, void* l) {
  __builtin_amdgcn_global_load_lds(
      (const __attribute__((address_space(1))) void*)g,
      (__attribute__((address_space(3))) void*)(uintptr_t)l,
      16, 0, 0);
}

// pack two f32 -> 2 f16 in one u32 (v_cvt_pkrtz_f16_f32)
static __device__ inline uint32_t pkrtz(float a, float b) {
  auto v = __builtin_amdgcn_cvt_pkrtz(a, b);
  return __builtin_bit_cast(uint32_t, v);
}
static __device__ inline float tanhfast(float x) {
  float e = __expf(2.f * x);
  return 1.f - 2.f / (e + 1.f);
}

// XCD-aware bijective remap on a sub-range slot s (range size 8*2^LG_C):
// o = ((s & (2^LG_C - 1)) << 3) | (s >> LG_C).
#define XCD_MAP(s, LG_C) ((int)((((s) & ((1u << (LG_C)) - 1)) << 3) | ((s) >> (LG_C))))

// ===========================================================================
// LAUNCH 1 (k_pre1, 2560 blocks):
//   blocks [0,512):   fused hmean partial sums + f16 image of h
//   blocks [512,2560): weight transpose/convert with BK=64 LDS bank-swizzle
//   baked in: within each row, 16B-chunk c stored at slot c^(row&7).
// ===========================================================================
__global__ void k_pre1(const float* __restrict__ h, float* __restrict__ hmean4,
                       f16* __restrict__ h16,
                       const float* __restrict__ Wa, const float* __restrict__ Wm,
                       const float* __restrict__ Wz, const float* __restrict__ Wr,
                       const float* __restrict__ Wh,
                       f16* __restrict__ WaT, f16* __restrict__ WmT,
                       f16* __restrict__ WzrT, f16* __restrict__ WhcT) {
  if (blockIdx.x < 512) {
    int u = blockIdx.x;
    int b = u & 127, part = u >> 7, d = threadIdx.x;
    size_t base = ((size_t)b * N_ + part * 128) * H_ + d;
    const float* p = h + base;
    f16* p16 = h16 + base;
    float s = 0.f;
    #pragma unroll 8
    for (int n = 0; n < 128; ++n) {
      float v = p[n * H_];
      s += v;
      p16[n * H_] = (f16)v;
    }
    hmean4[(b * 4 + part) * H_ + d] = s;
    return;
  }
  int idx = (blockIdx.x - 512) * 256 + threadIdx.x;
  if (idx < 65536) {
    int d = idx >> 8, k = idx & 255;
    int kk = ((((k >> 3) ^ (d & 7)) << 3) | (k & 7));
    WaT[d * 256 + kk] = (f16)Wa[k * 256 + d];
  } else if (idx < 131072) {
    int t = idx - 65536;
    int d = t >> 8, k = t & 255;
    int kk = ((((k >> 3) ^ (d & 7)) << 3) | (k & 7));
    WmT[d * 256 + kk] = (f16)Wm[k * 256 + d];
  } else if (idx < 131072 + 262144) {
    int t = idx - 131072;
    int n = t >> 9, k = t & 511;
    const float* src = (n < 256) ? Wz : Wr;
    int np  = n & 255;
    int row = (k < 256) ? k : (264 + k);   // 520 + (k - 256)
    int kk = ((((k >> 3) ^ (n & 7)) << 3) | (k & 7));
    WzrT[n * 512 + kk] = (f16)src[row * 256 + np];
  } else {
    int t = idx - (131072 + 262144);       // < 131072
    int n = t >> 9, k = t & 511;
    int row = (k < 256) ? k : (264 + k);
    int kk = ((((k >> 3) ^ (n & 7)) << 3) | (k & 7));
    WhcT[n * 512 + kk] = (f16)Wh[row * 256 + n];
  }
}

// ===========================================================================
// Shared GEMM geometry (R13, verified): 128x128 tile, 4 waves 2x2 (wave 64x64,
// acc[4][4]), BK=64, SINGLE-buffered LDS (32KB). m97-style loop:
//   stage(kt) -> vmcnt(0) -> barrier -> compute -> barrier.  Race-free.
// ===========================================================================
#define GEMM_PRE()                                                      \
  const int tid = threadIdx.x, lane = tid & 63, wave = tid >> 6;        \
  const int g = lane >> 4, m16 = lane & 15;                             \
  const int wr = (wave >> 1) * 64, wc = (wave & 1) * 64;                \
  f32x4 acc[4][4] = {};

#define GEMM_COMPUTE(Ab, Bb)                                            \
  _Pragma("unroll")                                                     \
  for (int ks = 0; ks < 2; ++ks) {                                      \
    f16x8 af[4], bf[4];                                                 \
    _Pragma("unroll")                                                   \
    for (int mi = 0; mi < 4; ++mi)                                      \
      af[mi] = *(const f16x8*)((const char*)(Ab) + (wr + mi * 16 + m16) * 128 \
                               + (((ks * 4 + g) ^ (m16 & 7)) << 4));    \
    _Pragma("unroll")                                                   \
    for (int ni = 0; ni < 4; ++ni)                                      \
      bf[ni] = *(const f16x8*)((const char*)(Bb) + (wc + ni * 16 + m16) * 128 \
                               + (((ks * 4 + g) ^ (m16 & 7)) << 4));    \
    _Pragma("unroll")                                                   \
    for (int mi = 0; mi < 4; ++mi)                                      \
      _Pragma("unroll")                                                 \
      for (int ni = 0; ni < 4; ++ni)                                    \
        acc[mi][ni] = MFMA16(af[mi], bf[ni], acc[mi][ni]);              \
  }

#define GEMM_LOOP1(KMAX, STGX, STGY)                                    \
  for (int kt = 0; kt < (KMAX) / 64; ++kt) {                            \
    STGX(kt * 64);                                                      \
    STGY(kt * 64);                                                      \
    asm volatile("s_waitcnt vmcnt(0)" ::: "memory");                    \
    __builtin_amdgcn_sched_barrier(0);                                  \
    __builtin_amdgcn_s_barrier();                                       \
    __builtin_amdgcn_sched_barrier(0);                                  \
    GEMM_COMPUTE(&AL[0], &BL[0]);                                       \
    __builtin_amdgcn_s_barrier();                                       \
    __builtin_amdgcn_sched_barrier(0);                                  \
  }

// per-lane source offsets (BK=64: 8 rows per gld16, lane l -> row l>>3, chunk l&7)
#define SRC_SWZ(row0) ((size_t)(row0 + wave * 32 + (lane >> 3)) * 512 \
                       + (size_t)(((lane & 7) ^ ((lane >> 3) & 7)) << 4))
#define SRC_IMG(row0, RS) ((size_t)(row0 + wave * 32 + (lane >> 3)) * (RS) \
                           + (size_t)((lane & 7) << 4))

// ===========================================================================
// LAUNCH 2 (k_mid, 2176 blocks): q GEMM [0,1024) | hmT GEMM [1024,2048) |
// cvec [2048,2176).  All depend only on launch-1 outputs; co-resident blocks
// fill each other's latency bubbles.
// ===========================================================================
__global__ __launch_bounds__(256) void k_mid(
    const f16* __restrict__ h16, const f16* __restrict__ WaT,
    const float* __restrict__ ba, f16* __restrict__ q,
    const f16* __restrict__ WmT, const float* __restrict__ bm,
    f16* __restrict__ hmT,
    const float* __restrict__ hmean4, const float* __restrict__ jets,
    const float* __restrict__ Wz, const float* __restrict__ Wr,
    const float* __restrict__ Wh,
    const float* __restrict__ bz, const float* __restrict__ br,
    const float* __restrict__ bh,
    float* __restrict__ cz, float* __restrict__ cr, float* __restrict__ ch) {
  __shared__ __align__(16) f16 AL[128 * 64], BL[128 * 64];
  if (blockIdx.x < 1024) {
    // ---------------- q = f16(h @ Wa + ba); o: n = o&1, m = o>>1
    GEMM_PRE();
    const int o = XCD_MAP(blockIdx.x, 7);       // C = 128
    const int m0 = (o >> 1) * 128, n0 = (o & 1) * 128;
    const size_t a_off = SRC_SWZ(m0);
    const size_t b_off = SRC_IMG(n0, 512);
    #define STGX_Q(k0)                                                  \
      {                                                                 \
        const char* sa = (const char*)h16 + a_off + (size_t)(k0) * 2;   \
        char* da = (char*)&AL[0] + wave * 4096;                         \
        _Pragma("unroll")                                               \
        for (int i_ = 0; i_ < 4; ++i_) gld16(sa + i_ * 4096, da + i_ * 1024); \
      }
    #define STGY_Q(k0)                                                  \
      {                                                                 \
        const char* sb = (const char*)WaT + b_off + (size_t)(k0) * 2;   \
        char* db = (char*)&BL[0] + wave * 4096;                         \
        _Pragma("unroll")                                               \
        for (int i_ = 0; i_ < 4; ++i_) gld16(sb + i_ * 4096, db + i_ * 1024); \
      }
    GEMM_LOOP1(256, STGX_Q, STGY_Q);
    #pragma unroll
    for (int mi = 0; mi < 4; ++mi)
      #pragma unroll
      for (int ni = 0; ni < 4; ++ni) {
        int gcol = n0 + wc + ni * 16 + m16;
        float bias = ba[gcol];
        #pragma unroll
        for (int r = 0; r < 4; ++r) {
          int grow = m0 + wr + mi * 16 + 4 * g + r;
          q[(size_t)grow * 256 + gcol] = (f16)(acc[mi][ni][r] + bias);
        }
      }
  } else if (blockIdx.x < 2048) {
    // ---------------- hmT[b][d][n] = f16((h[b]@Wm+bm)^T); o: tile=o&7, b=o>>3
    GEMM_PRE();
    const int o = XCD_MAP(blockIdx.x - 1024, 7);   // C = 128
    const int b = o >> 3;
    const int m0 = ((o & 7) >> 2) * 128, n0 = (o & 3) * 128;
    const size_t a_off = SRC_IMG(m0, 512);
    const size_t b_off = SRC_SWZ(b * 512 + n0);
    #define STGX_HM(k0)                                                 \
      {                                                                 \
        const char* sb = (const char*)h16 + b_off + (size_t)(k0) * 2;   \
        char* db = (char*)&BL[0] + wave * 4096;                         \
        _Pragma("unroll")                                               \
        for (int i_ = 0; i_ < 4; ++i_) gld16(sb + i_ * 4096, db + i_ * 1024); \
      }
    #define STGY_HM(k0)                                                 \
      {                                                                 \
        const char* sa = (const char*)WmT + a_off + (size_t)(k0) * 2;   \
        char* da = (char*)&AL[0] + wave * 4096;                         \
        _Pragma("unroll")                                               \
        for (int i_ = 0; i_ < 4; ++i_) gld16(sa + i_ * 4096, da + i_ * 1024); \
      }
    GEMM_LOOP1(256, STGX_HM, STGY_HM);
    #pragma unroll
    for (int mi = 0; mi < 4; ++mi)
      #pragma unroll
      for (int r = 0; r < 4; ++r) {
        int d = m0 + wr + mi * 16 + 4 * g + r;
        float bias = bm[d];
        #pragma unroll
        for (int ni = 0; ni < 4; ++ni) {
          int n = n0 + wc + ni * 16 + m16;
          hmT[(size_t)b * H_ * N_ + (size_t)d * N_ + n] = (f16)(acc[mi][ni][r] + bias);
        }
      }
  } else {
    // ---------------- cvec: per-batch GRU constants (aliases AL as LDS)
    float* hm = (float*)&AL[0];
    float* jt = hm + H_;
    int b = blockIdx.x - 2048, d = threadIdx.x;
    hm[d] = (hmean4[(b * 4 + 0) * H_ + d] + hmean4[(b * 4 + 1) * H_ + d] +
             hmean4[(b * 4 + 2) * H_ + d] + hmean4[(b * 4 + 3) * H_ + d]) * (1.f / N_);
    if (d < FJ) jt[d] = jets[b * FJ + d];
    __syncthreads();
    float az = bz[d], ar = br[d], ah = bh[d];
    #pragma unroll 4
    for (int k = 0; k < H_; ++k) {
      float m = hm[k];
      az += m * Wz[(256 + k) * 256 + d];
      ar += m * Wr[(256 + k) * 256 + d];
      ah += m * Wh[(256 + k) * 256 + d];
    }
    #pragma unroll
    for (int f = 0; f < FJ; ++f) {
      float j = jt[f];
      az += j * Wz[(512 + f) * 256 + d];
      ar += j * Wr[(512 + f) * 256 + d];
      ah += j * Wh[(512 + f) * 256 + d];
    }
    cz[b * H_ + d] = az;
    cr[b * H_ + d] = ar;
    ch[b * H_ + d] = ah;
  }
}

// ---------------------------------------------------------------------------
// Flash attention + DTNN message, v7 (UNCHANGED from R13 — passing).
// ---------------------------------------------------------------------------
__global__ __launch_bounds__(256, 2) void k_attn7(
    const f16* __restrict__ q, const float* __restrict__ mask,
    const f16* __restrict__ hmT, const f16* __restrict__ h16,
    f16* __restrict__ msg) {
  __shared__ __align__(16) f16 Kt[2][32 * 256];   // 2 x 16KB
  __shared__ __align__(16) f16 Vt[2][256 * 32];   // 2 x 16KB
  __shared__ float mask_lds[N_];
  const int tid = threadIdx.x, lane = tid & 63, wave = tid >> 6;
  const int l31 = lane & 31, hi = lane >> 5;
  const int o = XCD_MAP(blockIdx.x, 6);          // C = 64
  const int b = o & 127, i0 = (o >> 7) * 128 + wave * 32;

  mask_lds[tid]       = mask[b * N_ + tid];
  mask_lds[tid + 256] = mask[b * N_ + tid + 256];

  const f16* qrow = q + (size_t)(b * N_ + i0 + l31) * H_ + hi * 8;
  f16x8 qb[16];
  #pragma unroll
  for (int s5 = 0; s5 < 16; ++s5) qb[s5] = *(const f16x8*)(qrow + s5 * 16);

  f32x16 ot[8] = {};          // O^T: 8 d-tiles x 16 f32
  float mrun = -3.0e38f, lrun = 0.f;

  const char* hvbs = (const char*)(hmT + (size_t)b * H_ * N_);
  const char* h16b = (const char*)(h16 + (size_t)b * N_ * H_);

  auto stageK = [&](int buf, int jt) {
    const int rl = lane >> 5, s5 = lane & 31;
    char* dst = (char*)&Kt[buf][0] + wave * 4096;
    #pragma unroll
    for (int i = 0; i < 4; ++i) {
      int row = wave * 8 + i * 2 + rl;
      const char* src = h16b + (size_t)(jt * 32 + row) * 512
                      + (size_t)((s5 ^ (row & 7)) << 4);
      gld16(src, dst + i * 1024);
    }
  };
  auto stageV = [&](int buf, int jt) {
    const int swz = ((lane & 3) ^ ((lane >> 3) & 3)) << 4;
    char* dst = (char*)&Vt[buf][0] + wave * 4096;
    #pragma unroll
    for (int i = 0; i < 4; ++i) {
      int d = wave * 64 + i * 16 + (lane >> 2);
      gld16(hvbs + (size_t)d * 1024 + jt * 64 + swz, dst + i * 1024);
    }
  };

  __syncthreads();            // mask_lds visible before first use
  stageK(0, 0); stageV(0, 0); // 8 gld16
  __builtin_amdgcn_sched_barrier(0);

  const int x7 = lane & 7, x3 = (l31 >> 1) & 3;

  for (int jt = 0; jt < 16; ++jt) {
    const int cur = jt & 1, j0 = jt * 32;
    if (jt < 15) {
      stageK(cur ^ 1, jt + 1); stageV(cur ^ 1, jt + 1);
      asm volatile("s_waitcnt vmcnt(8)" ::: "memory");
    } else {
      asm volatile("s_waitcnt vmcnt(0)" ::: "memory");
    }
    __builtin_amdgcn_sched_barrier(0);
    __builtin_amdgcn_s_barrier();      // cur K/V visible; prev-buf reads done
    __builtin_amdgcn_sched_barrier(0);

    // ---- S^T = K · Q^T  (16 slabs of K=16)
    const char* kb = (const char*)&Kt[cur][0] + l31 * 512;
    f32x16 st = {};
    __builtin_amdgcn_s_setprio(1);
    #pragma unroll
    for (int s5 = 0; s5 < 16; ++s5) {
      f16x8 kf = *(const f16x8*)(kb + (((s5 * 2 + hi) ^ x7) << 4));
      st = MFMA32(kf, qb[s5], st);
    }
    __builtin_amdgcn_s_setprio(0);

    // ---- in-register online softmax
    float pm = st[0];
    #pragma unroll
    for (int r = 1; r < 16; ++r) pm = fmaxf(pm, st[r]);
    pm = fmaxf(pm, __shfl_xor(pm, 32, 64));
    if (!__all(pm <= mrun + 8.f)) {      // defer-max (T13)
      float mn = fmaxf(mrun, pm);
      float al = __expf(mrun - mn);
      lrun *= al;
      #pragma unroll
      for (int dt = 0; dt < 8; ++dt)
        #pragma unroll
        for (int e = 0; e < 16; ++e) ot[dt][e] *= al;
      mrun = mn;
    }
    float p[16], ts = 0.f;
    #pragma unroll
    for (int r = 0; r < 16; ++r) {
      float mk = mask_lds[j0 + (r & 3) + 8 * (r >> 2) + 4 * hi];
      p[r] = __expf(st[r] - mrun) * mk;
      ts += p[r];
    }
    ts += __shfl_xor(ts, 32, 64);
    lrun += ts;

    // ---- pack P -> f16 B-frags via shfl_xor(32) redistribution
    f16x8 pf[2];
    #pragma unroll
    for (int kk = 0; kk < 2; ++kk) {
      uint32_t pk01 = pkrtz(p[kk * 8 + 0], p[kk * 8 + 1]);
      uint32_t pk23 = pkrtz(p[kk * 8 + 2], p[kk * 8 + 3]);
      uint32_t pk45 = pkrtz(p[kk * 8 + 4], p[kk * 8 + 5]);
      uint32_t pk67 = pkrtz(p[kk * 8 + 6], p[kk * 8 + 7]);
      uint32_t s01 = __shfl_xor(pk01, 32, 64);
      uint32_t s23 = __shfl_xor(pk23, 32, 64);
      uint32_t s45 = __shfl_xor(pk45, 32, 64);
      uint32_t s67 = __shfl_xor(pk67, 32, 64);
      union { uint32_t u[4]; f16x8 v; } w;
      w.u[0] = hi ? s45 : pk01;
      w.u[1] = hi ? s67 : pk23;
      w.u[2] = hi ? pk45 : s01;
      w.u[3] = hi ? pk67 : s23;
      pf[kk] = w.v;
    }

    // ---- O^T += V^T · P^T
    const char* vb = (const char*)&Vt[cur][0] + l31 * 64;
    __builtin_amdgcn_s_setprio(1);
    #pragma unroll
    for (int kk = 0; kk < 2; ++kk)
      #pragma unroll
      for (int dt = 0; dt < 8; ++dt) {
        f16x8 vf = *(const f16x8*)(vb + dt * 2048 + (((kk * 2 + hi) ^ x3) << 4));
        ot[dt] = MFMA32(vf, pf[kk], ot[dt]);
      }
    __builtin_amdgcn_s_setprio(0);

    __builtin_amdgcn_s_barrier();      // all reads of cur done before overwrite
    __builtin_amdgcn_sched_barrier(0);
  }

  // ---- epilogue: msg[i][d] = tanh(rm * O^T[d][i] / l), packed 8B stores
  float rm  = mask_lds[i0 + l31];
  float inv = rm / lrun;
  f16* msgp = msg + (size_t)(b * N_ + i0 + l31) * H_;
  #pragma unroll
  for (int dt = 0; dt < 8; ++dt)
    #pragma unroll
    for (int rg = 0; rg < 4; ++rg) {
      float t0 = tanhfast(ot[dt][rg * 4 + 0] * inv);
      float t1 = tanhfast(ot[dt][rg * 4 + 1] * inv);
      float t2 = tanhfast(ot[dt][rg * 4 + 2] * inv);
      float t3 = tanhfast(ot[dt][rg * 4 + 3] * inv);
      union { uint32_t u[2]; uint64_t q; } w;
      w.u[0] = pkrtz(t0, t1); w.u[1] = pkrtz(t2, t3);
      *(uint64_t*)(msgp + dt * 32 + rg * 8 + 4 * hi) = w.q;
    }
}

// ---------------------------------------------------------------------------
// Gate GEMM 1 (R13): pre = [msg|h] @ Wzr + c. 2048 blocks; o: n = o&3, m = o>>2.
// ---------------------------------------------------------------------------
__global__ __launch_bounds__(256) void k_gemm_zr(
    const f16* __restrict__ msg, const f16* __restrict__ h16,
    const f16* __restrict__ WzrT, const float* __restrict__ cz,
    const float* __restrict__ cr, f16* __restrict__ z, f16* __restrict__ rh) {
  __shared__ __align__(16) f16 AL[128 * 64], BL[128 * 64];
  GEMM_PRE();
  const int o = XCD_MAP(blockIdx.x, 8);         // C = 256
  const int m0 = (o >> 2) * 128;
  const int nx = o & 3;
  const int n0 = nx * 128;
  const size_t a_off = SRC_SWZ(m0);
  const size_t b_off = SRC_IMG(n0, 1024);
  #define STGX_ZR(k0)                                                   \
    {                                                                   \
      const char* ab = (const char*)((k0) < 256 ? msg : h16);           \
      const char* sa = ab + a_off + (size_t)(((k0) & 255)) * 2;         \
      char* da = (char*)&AL[0] + wave * 4096;                           \
      _Pragma("unroll")                                                 \
      for (int i_ = 0; i_ < 4; ++i_) gld16(sa + i_ * 4096, da + i_ * 1024); \
    }
  #define STGY_ZR(k0)                                                   \
    {                                                                   \
      const char* sb = (const char*)WzrT + b_off + (size_t)(k0) * 2;    \
      char* db = (char*)&BL[0] + wave * 4096;                           \
      _Pragma("unroll")                                                 \
      for (int i_ = 0; i_ < 4; ++i_) gld16(sb + i_ * 8192, db + i_ * 1024); \
    }
  GEMM_LOOP1(512, STGX_ZR, STGY_ZR);
  const int is_r = nx >> 1;
  #pragma unroll
  for (int mi = 0; mi < 4; ++mi)
    #pragma unroll
    for (int ni = 0; ni < 4; ++ni) {
      int ncol = (nx & 1) * 128 + wc + ni * 16 + m16;
      #pragma unroll
      for (int r = 0; r < 4; ++r) {
        int grow = m0 + wr + mi * 16 + 4 * g + r;
        int bb = grow >> 9;
        float a = acc[mi][ni][r];
        size_t oidx = (size_t)grow * 256 + ncol;
        if (!is_r) {
          float v = a + cz[bb * 256 + ncol];
          z[oidx] = (f16)(1.f / (1.f + __expf(-v)));
        } else {
          float v  = a + cr[bb * 256 + ncol];
          float rr = 1.f / (1.f + __expf(-v));
          rh[oidx] = (f16)(rr * (float)h16[oidx]);
        }
      }
    }
}

// ---------------------------------------------------------------------------
// Gate GEMM 2 (R13): h_tilde = tanh([msg|rh] @ Whc + c_h);
// out = (1-z)*h + z*h_tilde. 1024 blocks; o: n = o&1, m = o>>1.
// ---------------------------------------------------------------------------
__global__ __launch_bounds__(256) void k_gemm_ht(
    const f16* __restrict__ msg, const f16* __restrict__ rh,
    const f16* __restrict__ WhcT, const float* __restrict__ ch,
    const f16* __restrict__ z, const f16* __restrict__ h16,
    float* __restrict__ out) {
  __shared__ __align__(16) f16 AL[128 * 64], BL[128 * 64];
  GEMM_PRE();
  const int o = XCD_MAP(blockIdx.x, 7);         // C = 128
  const int m0 = (o >> 1) * 128;
  const int n0 = (o & 1) * 128;
  const size_t a_off = SRC_SWZ(m0);
  const size_t b_off = SRC_IMG(n0, 1024);
  #define STGX_HT(k0)                                                   \
    {                                                                   \
      const char* ab = (const char*)((k0) < 256 ? msg : rh);            \
      const char* sa = ab + a_off + (size_t)(((k0) & 255)) * 2;         \
      char* da = (char*)&AL[0] + wave * 4096;                           \
      _Pragma("unroll")                                                 \
      for (int i_ = 0; i_ < 4; ++i_) gld16(sa + i_ * 4096, da + i_ * 1024); \
    }
  #define STGY_HT(k0)                                                   \
    {                                                                   \
      const char* sb = (const char*)WhcT + b_off + (size_t)(k0) * 2;    \
      char* db = (char*)&BL[0] + wave * 4096;                           \
      _Pragma("unroll")                                                 \
      for (int i_ = 0; i_ < 4; ++i_) gld16(sb + i_ * 8192, db + i_ * 1024); \
    }
  GEMM_LOOP1(512, STGX_HT, STGY_HT);
  #pragma unroll
  for (int mi = 0; mi < 4; ++mi)
    #pragma unroll
    for (int ni = 0; ni < 4; ++ni) {
      int gcol = n0 + wc + ni * 16 + m16;
      #pragma unroll
      for (int r = 0; r < 4; ++r) {
        int grow = m0 + wr + mi * 16 + 4 * g + r;
        int bb = grow >> 9;
        size_t oidx = (size_t)grow * 256 + gcol;
        float pre = acc[mi][ni][r] + ch[bb * 256 + gcol];
        float htl = tanhf(pre);
        float zv  = (float)z[oidx];
        float hv  = (float)h16[oidx];
        out[oidx] = (1.f - zv) * hv + zv * htl;
      }
    }
}

// ---------------------------------------------------------------------------
extern "C" void kernel_launch(void* const* d_in, const int* in_sizes, int n_in,
                              void* d_out, int out_size, void* d_ws, size_t ws_size,
                              hipStream_t stream) {
  const float* h    = (const float*)d_in[0];
  const float* jets = (const float*)d_in[1];
  const float* mask = (const float*)d_in[2];
  const float* Wa   = (const float*)d_in[3];
  const float* ba   = (const float*)d_in[4];
  const float* Wm   = (const float*)d_in[5];
  const float* bm   = (const float*)d_in[6];
  const float* Wz   = (const float*)d_in[7];
  const float* bz   = (const float*)d_in[8];
  const float* Wr   = (const float*)d_in[9];
  const float* br   = (const float*)d_in[10];
  const float* Wh   = (const float*)d_in[11];
  const float* bh   = (const float*)d_in[12];
  float* out = (float*)d_out;

  char* ws = (char*)d_ws;
  size_t off = 0;
  auto alloc = [&](size_t bytes) -> void* {
    void* p = ws + off;
    off += (bytes + 255) & ~(size_t)255;
    return p;
  };
  // big: q (f16, 32MB) during attention; z (f16) + rh (f16) afterwards.
  char*   big   = (char*) alloc((size_t)ROWS * H_ * 4);
  f16*    hmT   = (f16*)  alloc((size_t)B_ * H_ * N_ * 2);
  f16*    msg   = (f16*)  alloc((size_t)ROWS * H_ * 2);
  f16*    h16   = (f16*)  alloc((size_t)ROWS * H_ * 2);
  float*  hmean4= (float*)alloc((size_t)B_ * 4 * H_ * 4);
  float*  cz    = (float*)alloc((size_t)B_ * H_ * 4);
  float*  cr    = (float*)alloc((size_t)B_ * H_ * 4);
  float*  chv   = (float*)alloc((size_t)B_ * H_ * 4);
  f16*    WaT   = (f16*)  alloc(65536 * 2);
  f16*    WmT   = (f16*)  alloc(65536 * 2);
  f16*    WzrT  = (f16*)  alloc(262144 * 2);
  f16*    WhcT  = (f16*)  alloc(131072 * 2);
  f16* q  = (f16*)big;
  f16* z  = (f16*)big;                                     // q dead after attn
  f16* rh = (f16*)(big + (size_t)ROWS * H_ * 2);
  if (off > ws_size) return;  // workspace insufficient

  k_pre1   <<<2560, 256, 0, stream>>>(h, hmean4, h16,
                                      Wa, Wm, Wz, Wr, Wh, WaT, WmT, WzrT, WhcT);
  k_mid    <<<2176, 256, 0, stream>>>(h16, WaT, ba, q, WmT, bm, hmT,
                                      hmean4, jets, Wz, Wr, Wh, bz, br, bh,
                                      cz, cr, chv);
  k_attn7  <<<512, 256, 0, stream>>>(q, mask, hmT, h16, msg);
  k_gemm_zr<<<2048, 256, 0, stream>>>(msg, h16, WzrT, cz, cr, z, rh);
  k_gemm_ht<<<1024, 256, 0, stream>>>(msg, rh, WhcT, chv, z, h16, out);
}